// Round 1
// baseline (2581.850 us; speedup 1.0000x reference)
//
#include <hip/hip_runtime.h>
#include <math.h>

// Problem constants (fixed by setup_inputs): B=2, d_model=192 -> 2 cores of c=96,
// K=4, d_state=8, dt_rank=12, H=W=64, L=4096.

// ws layout in floats:
//  delta [core][b][k][d][l] : 16*96*4096 = 6291456
//  Bst   [core][b][k][l][n] : 16*4096*8  = 524288
//  Cst   [core][b][k][l][n] : 524288
//  outv  [core][b][k][d][l] : 6291456
#define OFF_DELTA 0L
#define OFF_BST   6291456L
#define OFF_CST   6815744L
#define OFF_OUTV  7340032L

__device__ __forceinline__ float softplus_f(float x) {
  return fmaxf(x, 0.0f) + log1pf(expf(-fabsf(x)));
}

// ---------------------------------------------------------------------------
// Kernel 1: per (core,b,k, l-tile of 64): stage xs tile (index transform of
// Fin) in LDS, compute x_dbl (28 outputs/l), write Bs,Cs (transposed [l][n])
// and delta = softplus(dts . dtw + dtb) to ws.
// ---------------------------------------------------------------------------
__global__ __launch_bounds__(256) void ss2d_prep(
    const float* __restrict__ Fin,    // [2][192][4096]
    const float* __restrict__ xproj,  // [4][28][96]
    const float* __restrict__ dtw,    // [4][96][12]
    const float* __restrict__ dtb,    // [4][96]
    float* __restrict__ ws)
{
  __shared__ float xt[96][64];
  __shared__ float wp[28][96];
  __shared__ float dwL[96][12];
  __shared__ float dtbL[96];
  __shared__ float dtsL[12][64];

  const int bid  = blockIdx.x;
  const int tile = bid & 63;
  const int k    = (bid >> 6) & 3;
  const int b    = (bid >> 8) & 1;
  const int core = bid >> 9;
  const int tid  = threadIdx.x;
  const int l0   = tile << 6;
  const int h0   = tile;          // l>>6 for this tile (l0 is 64-aligned)

  float* wpf = &wp[0][0];
  for (int i = tid; i < 28*96; i += 256) wpf[i] = xproj[k*28*96 + i];
  float* dwf = &dwL[0][0];
  for (int i = tid; i < 96*12; i += 256) dwf[i] = dtw[k*96*12 + i];
  if (tid < 96) dtbL[tid] = dtb[k*96 + tid];

  // xs[b,k,d,l]: k=0: Fin[...,l]; k=1: transpose; k=2: flip; k=3: flip∘transpose
  const float* finB = Fin + ((long)b*192 + core*96) * 4096;
  for (int i = tid; i < 96*64; i += 256) {
    int d = i >> 6, ll = i & 63;
    int l = l0 + ll;
    int pos;
    if (k == 0)      pos = l;
    else if (k == 1) pos = (ll << 6) | h0;
    else if (k == 2) pos = 4095 - l;
    else             pos = 4095 - ((ll << 6) | h0);
    xt[d][ll] = finB[d*4096 + pos];
  }
  __syncthreads();

  const int cbk = (core*2 + b)*4 + k;

  // x_dbl[cc][ll] = sum_d xs[d][ll] * Wproj[k][cc][d]
  for (int i = tid; i < 28*64; i += 256) {
    int cc = i >> 6, ll = i & 63;
    float acc = 0.f;
    for (int d = 0; d < 96; ++d) acc += xt[d][ll] * wp[cc][d];
    if (cc < 12) {
      dtsL[cc][ll] = acc;
    } else {
      long base = ((long)cbk*4096 + (l0 + ll)) * 8;
      if (cc < 20) ws[OFF_BST + base + (cc-12)] = acc;
      else         ws[OFF_CST + base + (cc-20)] = acc;
    }
  }
  __syncthreads();

  // delta[d][ll] = softplus(sum_r dts[r][ll]*dtw[d][r] + dtb[d])
  for (int i = tid; i < 96*64; i += 256) {
    int d = i >> 6, ll = i & 63;
    float s = dtbL[d];
    #pragma unroll
    for (int r = 0; r < 12; ++r) s += dtsL[r][ll] * dwL[d][r];
    ws[OFF_DELTA + ((long)cbk*96 + d)*4096 + l0 + ll] = softplus_f(s);
  }
}

// ---------------------------------------------------------------------------
// Kernel 2: the sequential scan. 8 lanes per (core,b,k,d) scan; lane = state
// index n. 1536 scans -> 192 single-wave blocks. MLP via 3x butterfly
// allgather (__shfl_xor within 8) with per-lane pre-rotated weights.
// Writes out = y + xs*Ds.
// ---------------------------------------------------------------------------
__global__ __launch_bounds__(64) void ss2d_scan(
    const float* __restrict__ Fin,
    const float* __restrict__ Alogs,  // [4][96][8]
    const float* __restrict__ DsArr,  // [4][96]
    const float* __restrict__ w1, const float* __restrict__ b1,
    const float* __restrict__ w2, const float* __restrict__ b2,
    const float* __restrict__ w3, const float* __restrict__ b3,
    float* __restrict__ ws)
{
  const int tid  = threadIdx.x;
  const int n    = tid & 7;
  const int G    = blockIdx.x * 8 + (tid >> 3);
  const int d    = G % 96;
  const int t3   = G / 96;            // == (core*2+b)*4 + k
  const int k    = t3 & 3;
  const int b    = (t3 >> 2) & 1;
  const int core = t3 >> 3;

  // pre-rotated MLP weights: lane n computes out[n] = b[n] + sum_t h[n^t]*w[n][n^t]
  float wl1[8], wl2[8], wl3[8];
  #pragma unroll
  for (int t = 0; t < 8; ++t) {
    int i = n ^ t;
    wl1[t] = w1[n*8 + i];
    wl2[t] = w2[n*8 + i];
    wl3[t] = w3[n*8 + i];
  }
  const float b1v = b1[n], b2v = b2[n], b3v = b3[n];
  const float Av  = -expf(Alogs[(k*96 + d)*8 + n]);
  const float a2  = Av * 1.4426950408889634f;   // A * log2(e)
  const float dsv = DsArr[k*96 + d];

  const float* deltaP = ws + OFF_DELTA + ((long)t3*96 + d)*4096;
  const float* BstP   = ws + OFF_BST  + (long)t3*4096*8 + n;
  const float* CstP   = ws + OFF_CST  + (long)t3*4096*8 + n;
  float*       outP   = ws + OFF_OUTV + ((long)t3*96 + d)*4096;
  const float* finP   = Fin + ((long)b*192 + core*96 + d)*4096;

  float h = 0.f;
  for (int l = 0; l < 4096; ++l) {
    int pos;
    if (k == 0)      pos = l;
    else if (k == 1) pos = ((l & 63) << 6) | (l >> 6);
    else if (k == 2) pos = 4095 - l;
    else             pos = 4095 - (((l & 63) << 6) | (l >> 6));

    const float delta = deltaP[l];
    const float xv    = finP[pos];
    const float Bn    = BstP[(long)l*8];
    const float Cn    = CstP[(long)l*8];

    // ---- MLP(h): layer 1
    float v0 = h;
    float v1 = __shfl_xor(v0, 1, 8);
    float v2 = __shfl_xor(v0, 2, 8);
    float v3 = __shfl_xor(v1, 2, 8);
    float v4 = __shfl_xor(v0, 4, 8);
    float v5 = __shfl_xor(v1, 4, 8);
    float v6 = __shfl_xor(v2, 4, 8);
    float v7 = __shfl_xor(v3, 4, 8);
    float o = fmaf(v0, wl1[0], b1v);
    o = fmaf(v1, wl1[1], o); o = fmaf(v2, wl1[2], o); o = fmaf(v3, wl1[3], o);
    o = fmaf(v4, wl1[4], o); o = fmaf(v5, wl1[5], o); o = fmaf(v6, wl1[6], o);
    o = fmaf(v7, wl1[7], o);
    o = fmaxf(o, 0.f);
    // ---- layer 2
    v0 = o;
    v1 = __shfl_xor(v0, 1, 8);
    v2 = __shfl_xor(v0, 2, 8);
    v3 = __shfl_xor(v1, 2, 8);
    v4 = __shfl_xor(v0, 4, 8);
    v5 = __shfl_xor(v1, 4, 8);
    v6 = __shfl_xor(v2, 4, 8);
    v7 = __shfl_xor(v3, 4, 8);
    o = fmaf(v0, wl2[0], b2v);
    o = fmaf(v1, wl2[1], o); o = fmaf(v2, wl2[2], o); o = fmaf(v3, wl2[3], o);
    o = fmaf(v4, wl2[4], o); o = fmaf(v5, wl2[5], o); o = fmaf(v6, wl2[6], o);
    o = fmaf(v7, wl2[7], o);
    o = fmaxf(o, 0.f);
    // ---- layer 3
    v0 = o;
    v1 = __shfl_xor(v0, 1, 8);
    v2 = __shfl_xor(v0, 2, 8);
    v3 = __shfl_xor(v1, 2, 8);
    v4 = __shfl_xor(v0, 4, 8);
    v5 = __shfl_xor(v1, 4, 8);
    v6 = __shfl_xor(v2, 4, 8);
    v7 = __shfl_xor(v3, 4, 8);
    o = fmaf(v0, wl3[0], b3v);
    o = fmaf(v1, wl3[1], o); o = fmaf(v2, wl3[2], o); o = fmaf(v3, wl3[3], o);
    o = fmaf(v4, wl3[4], o); o = fmaf(v5, wl3[5], o); o = fmaf(v6, wl3[6], o);
    o = fmaf(v7, wl3[7], o);
    const float hw = o;

    // ---- state update + output
    const float dA  = exp2f(delta * a2);
    const float dBu = delta * Bn * xv;
    h = fmaf(dA, h, hw * dBu);

    float p = h * Cn;
    p += __shfl_xor(p, 1, 8);
    p += __shfl_xor(p, 2, 8);
    p += __shfl_xor(p, 4, 8);
    if (n == 0) outP[l] = fmaf(xv, dsv, p);
  }
}

// ---------------------------------------------------------------------------
// Kernel 3: per (core,b,h): gather 4 directional terms, sum, layernorm over
// c=96, write coalesced to d_out.
// ---------------------------------------------------------------------------
__global__ __launch_bounds__(256) void ss2d_final(
    const float* __restrict__ ws,
    const float* __restrict__ gamma,
    const float* __restrict__ beta,
    float* __restrict__ outp)
{
  __shared__ float sY[96][65];
  __shared__ float pS[4][64];
  __shared__ float pQ[4][64];
  __shared__ float mv[64];
  __shared__ float rs[64];

  const int bid = blockIdx.x;
  const int h   = bid & 63;
  const int b   = (bid >> 6) & 1;
  const int t   = (bid >> 7) & 1;   // core
  const int tid = threadIdx.x;
  const long cb4 = ((long)t*2 + b)*4;
  const float* outv = ws + OFF_OUTV;

  for (int i = tid; i < 96*64; i += 256) {
    int d = i >> 6, w = i & 63;
    int l  = (h << 6) | w;
    int lt = (w << 6) | h;
    float v0 = outv[((cb4+0)*96 + d)*4096 + l];
    float v1 = outv[((cb4+1)*96 + d)*4096 + lt];
    float v2 = outv[((cb4+2)*96 + d)*4096 + (4095 - l)];
    float v3 = outv[((cb4+3)*96 + d)*4096 + (4095 - lt)];
    sY[d][w] = v0 + v1 + v2 + v3;
  }
  __syncthreads();

  {
    int w = tid & 63, part = tid >> 6;
    float s = 0.f, q = 0.f;
    #pragma unroll
    for (int j = 0; j < 24; ++j) {
      float v = sY[part*24 + j][w];
      s += v; q += v*v;
    }
    pS[part][w] = s; pQ[part][w] = q;
  }
  __syncthreads();
  if (tid < 64) {
    int w = tid;
    float s = pS[0][w] + pS[1][w] + pS[2][w] + pS[3][w];
    float q = pQ[0][w] + pQ[1][w] + pQ[2][w] + pQ[3][w];
    float m = s * (1.0f/96.0f);
    float var = q * (1.0f/96.0f) - m*m;
    mv[w] = m;
    rs[w] = rsqrtf(var + 1e-5f);
  }
  __syncthreads();

  const long obase = (((long)t*2 + b)*4096 + (long)h*64)*96;
  for (int i = tid; i < 96*64; i += 256) {
    int w = i / 96, d = i - w*96;
    float v = (sY[d][w] - mv[w]) * rs[w] * gamma[d] + beta[d];
    outp[obase + (long)w*96 + d] = v;
  }
}

// ---------------------------------------------------------------------------
extern "C" void kernel_launch(void* const* d_in, const int* in_sizes, int n_in,
                              void* d_out, int out_size, void* d_ws, size_t ws_size,
                              hipStream_t stream)
{
  const float* Fin   = (const float*)d_in[0];
  const float* xproj = (const float*)d_in[1];
  const float* dtw   = (const float*)d_in[2];
  const float* dtb   = (const float*)d_in[3];
  const float* Alog  = (const float*)d_in[4];
  const float* Ds    = (const float*)d_in[5];
  const float* w1    = (const float*)d_in[6];
  const float* b1    = (const float*)d_in[7];
  const float* w2    = (const float*)d_in[8];
  const float* b2    = (const float*)d_in[9];
  const float* w3    = (const float*)d_in[10];
  const float* b3    = (const float*)d_in[11];
  const float* gamma = (const float*)d_in[12];
  const float* beta  = (const float*)d_in[13];
  float* ws   = (float*)d_ws;
  float* outp = (float*)d_out;

  ss2d_prep <<<dim3(1024), dim3(256), 0, stream>>>(Fin, xproj, dtw, dtb, ws);
  ss2d_scan <<<dim3(192),  dim3(64),  0, stream>>>(Fin, Alog, Ds, w1, b1, w2, b2, w3, b3, ws);
  ss2d_final<<<dim3(256),  dim3(256), 0, stream>>>(ws, gamma, beta, outp);
}

// Round 2
// 688.477 us; speedup vs baseline: 3.7501x; 3.7501x over previous
//
#include <hip/hip_runtime.h>
#include <math.h>

// Problem constants: B=2, d_model=192 -> 2 cores of c=96, K=4, d_state=8,
// dt_rank=12, H=W=64, L=4096.

// ws layout in floats:
//  delta [t3][d][l] : 16*96*4096 = 6291456   (t3 = (core*2+b)*4+k)
//  du    [t3][d][l] : 6291456                (du = delta * xs)
//  Bst   [t3][l/4][n][4] : 16*4096*8 = 524288
//  Cst   [t3][l/4][n][4] : 524288
//  outv  : ALIASES delta (each (t3,d) row is fully consumed 8+ steps ahead
//          of the write to the same index, within one wave)
#define OFF_DELTA 0L
#define OFF_DU    6291456L
#define OFF_BST   12582912L
#define OFF_CST   13107200L

#define QPX1 0xB1   // quad_perm [1,0,3,2]  -> lane ^ 1
#define QPX2 0x4E   // quad_perm [2,3,0,1]  -> lane ^ 2
#define QPX3 0x1B   // quad_perm [3,2,1,0]  -> lane ^ 3
#define RHM  0x141  // row_half_mirror      -> lane ^ 7 (within 8)

template<int CTRL>
__device__ __forceinline__ float dppf(float x) {
  int r = __builtin_amdgcn_update_dpp(0, __float_as_int(x), CTRL, 0xF, 0xF, true);
  return __int_as_float(r);
}

__device__ __forceinline__ float softplus_f(float x) {
  return fmaxf(x, 0.0f) + log1pf(expf(-fabsf(x)));
}

// ---------------------------------------------------------------------------
// Kernel 1: per (core,b,k, l-tile of 64): stage xs tile in LDS, compute
// x_dbl, write Bs,Cs (interleaved [l/4][n][4]) and delta + du = delta*xs.
// ---------------------------------------------------------------------------
__global__ __launch_bounds__(256) void ss2d_prep(
    const float* __restrict__ Fin,    // [2][192][4096]
    const float* __restrict__ xproj,  // [4][28][96]
    const float* __restrict__ dtw,    // [4][96][12]
    const float* __restrict__ dtb,    // [4][96]
    float* __restrict__ ws)
{
  __shared__ float xt[96][64];
  __shared__ float wp[28][96];
  __shared__ float dwL[96][12];
  __shared__ float dtbL[96];
  __shared__ float dtsL[12][64];

  const int bid  = blockIdx.x;
  const int tile = bid & 63;
  const int k    = (bid >> 6) & 3;
  const int b    = (bid >> 8) & 1;
  const int core = bid >> 9;
  const int tid  = threadIdx.x;
  const int l0   = tile << 6;
  const int h0   = tile;

  float* wpf = &wp[0][0];
  for (int i = tid; i < 28*96; i += 256) wpf[i] = xproj[k*28*96 + i];
  float* dwf = &dwL[0][0];
  for (int i = tid; i < 96*12; i += 256) dwf[i] = dtw[k*96*12 + i];
  if (tid < 96) dtbL[tid] = dtb[k*96 + tid];

  const float* finB = Fin + ((long)b*192 + core*96) * 4096;
  for (int i = tid; i < 96*64; i += 256) {
    int d = i >> 6, ll = i & 63;
    int l = l0 + ll;
    int pos;
    if (k == 0)      pos = l;
    else if (k == 1) pos = (ll << 6) | h0;
    else if (k == 2) pos = 4095 - l;
    else             pos = 4095 - ((ll << 6) | h0);
    xt[d][ll] = finB[d*4096 + pos];
  }
  __syncthreads();

  const int cbk = (core*2 + b)*4 + k;

  for (int i = tid; i < 28*64; i += 256) {
    int cc = i >> 6, ll = i & 63;
    float acc = 0.f;
    for (int d = 0; d < 96; ++d) acc += xt[d][ll] * wp[cc][d];
    int l = l0 + ll;
    if (cc < 12) {
      dtsL[cc][ll] = acc;
    } else {
      long base = (long)cbk*32768 + (long)(l >> 2)*32 + (l & 3);
      if (cc < 20) ws[OFF_BST + base + (cc-12)*4] = acc;
      else         ws[OFF_CST + base + (cc-20)*4] = acc;
    }
  }
  __syncthreads();

  for (int i = tid; i < 96*64; i += 256) {
    int d = i >> 6, ll = i & 63;
    float s = dtbL[d];
    #pragma unroll
    for (int r = 0; r < 12; ++r) s += dtsL[r][ll] * dwL[d][r];
    float dl = softplus_f(s);
    long off = ((long)cbk*96 + d)*4096 + l0 + ll;
    ws[OFF_DELTA + off] = dl;
    ws[OFF_DU    + off] = dl * xt[d][ll];
  }
}

// ---------------------------------------------------------------------------
// Kernel 2: sequential scan. 8 lanes per (t3,d) scan, lane = state index n.
// All cross-lane via DPP (VALU pipe): quad_perm xor1/2/3 + row_half_mirror
// compose to the full 8-lane allgather at depth 2, ~4-8 cyc per hop.
// 8-step blocks, distance-1 block prefetch of delta/du/B/C streams.
// ---------------------------------------------------------------------------
union B8 { float4 q[2]; float v[8]; };

__device__ __forceinline__ float mlp_layer(float h, const float wl[8], float bv) {
  float v0 = h;
  float v1 = dppf<QPX1>(v0);
  float v2 = dppf<QPX2>(v0);
  float v3 = dppf<QPX3>(v0);
  float v7 = dppf<RHM>(v0);
  float v6 = dppf<RHM>(v1);
  float v5 = dppf<RHM>(v2);
  float v4 = dppf<RHM>(v3);
  float o = fmaf(v0, wl[0], bv);
  o = fmaf(v1, wl[1], o); o = fmaf(v2, wl[2], o); o = fmaf(v3, wl[3], o);
  o = fmaf(v4, wl[4], o); o = fmaf(v5, wl[5], o); o = fmaf(v6, wl[6], o);
  o = fmaf(v7, wl[7], o);
  return o;
}

__global__ __launch_bounds__(64) void ss2d_scan(
    const float* __restrict__ Alogs,  // [4][96][8]
    const float* __restrict__ w1, const float* __restrict__ b1,
    const float* __restrict__ w2, const float* __restrict__ b2,
    const float* __restrict__ w3, const float* __restrict__ b3,
    float* __restrict__ ws)
{
  const int tid  = threadIdx.x;
  const int n    = tid & 7;
  const int G    = blockIdx.x * 8 + (tid >> 3);
  const int d    = G % 96;
  const int t3   = G / 96;
  const int k    = t3 & 3;

  float wl1[8], wl2[8], wl3[8];
  #pragma unroll
  for (int t = 0; t < 8; ++t) {
    int i = n ^ t;
    wl1[t] = w1[n*8 + i];
    wl2[t] = w2[n*8 + i];
    wl3[t] = w3[n*8 + i];
  }
  const float b1v = b1[n], b2v = b2[n], b3v = b3[n];
  const float a2  = -expf(Alogs[(k*96 + d)*8 + n]) * 1.4426950408889634f;

  const float* deltaP = ws + OFF_DELTA + ((long)t3*96 + d)*4096;
  const float* duP    = ws + OFF_DU    + ((long)t3*96 + d)*4096;
  float*       outP   = ws + OFF_DELTA + ((long)t3*96 + d)*4096;  // alias
  const float4* dQ = (const float4*)deltaP;
  const float4* uQ = (const float4*)duP;
  const float4* bQ = (const float4*)(ws + OFF_BST) + (long)t3*8192 + n;
  const float4* cQ = (const float4*)(ws + OFF_CST) + (long)t3*8192 + n;

  B8 cd, cu, cb, cc, nd, nu, nb, nc;
  // block 0 -> current, block 1 -> next
  cd.q[0] = dQ[0];  cd.q[1] = dQ[1];
  cu.q[0] = uQ[0];  cu.q[1] = uQ[1];
  cb.q[0] = bQ[0];  cb.q[1] = bQ[8];
  cc.q[0] = cQ[0];  cc.q[1] = cQ[8];
  nd.q[0] = dQ[2];  nd.q[1] = dQ[3];
  nu.q[0] = uQ[2];  nu.q[1] = uQ[3];
  nb.q[0] = bQ[16]; nb.q[1] = bQ[24];
  nc.q[0] = cQ[16]; nc.q[1] = cQ[24];

  float h = 0.f;
  for (int blk = 0; blk < 512; ++blk) {
    B8 ov;
    const int l0 = blk << 3;
    #pragma unroll
    for (int s = 0; s < 8; ++s) {
      float t1 = fmaxf(mlp_layer(h,  wl1, b1v), 0.f);
      float t2 = fmaxf(mlp_layer(t1, wl2, b2v), 0.f);
      float hw = mlp_layer(t2, wl3, b3v);
      float dA = exp2f(cd.v[s] * a2);
      h = fmaf(dA, h, hw * (cu.v[s] * cb.v[s]));
      float p = h * cc.v[s];
      p += dppf<QPX1>(p);
      p += dppf<QPX2>(p);
      p += dppf<RHM>(p);   // quad-uniform by now, so ^7 lands in the other quad
      ov.v[s] = p;
    }
    if (n == 0) {
      ((float4*)(outP + l0))[0] = ov.q[0];
      ((float4*)(outP + l0))[1] = ov.q[1];
    }
    // rotate and prefetch blk+2 (clamped; dup loads at the tail are unused)
    cd = nd; cu = nu; cb = nb; cc = nc;
    const int pb = (blk + 2 < 512) ? (blk + 2) : 511;
    nd.q[0] = dQ[pb*2];     nd.q[1] = dQ[pb*2 + 1];
    nu.q[0] = uQ[pb*2];     nu.q[1] = uQ[pb*2 + 1];
    nb.q[0] = bQ[pb*16];    nb.q[1] = bQ[pb*16 + 8];
    nc.q[0] = cQ[pb*16];    nc.q[1] = cQ[pb*16 + 8];
  }
}

// ---------------------------------------------------------------------------
// Kernel 3: per (core,b,h): gather 4 directional terms (index transforms),
// add Fin*sum_k(Ds) (the xs*Ds skip term collapses to this after the
// inverse transforms), sum, layernorm over c=96, write coalesced.
// ---------------------------------------------------------------------------
__global__ __launch_bounds__(256) void ss2d_final(
    const float* __restrict__ ws,
    const float* __restrict__ Fin,
    const float* __restrict__ DsArr,   // [4][96]
    const float* __restrict__ gamma,
    const float* __restrict__ beta,
    float* __restrict__ outp)
{
  __shared__ float sY[96][65];
  __shared__ float pS[4][64];
  __shared__ float pQ[4][64];
  __shared__ float mv[64];
  __shared__ float rs[64];
  __shared__ float dsumL[96];

  const int bid = blockIdx.x;
  const int h   = bid & 63;
  const int b   = (bid >> 6) & 1;
  const int t   = (bid >> 7) & 1;   // core
  const int tid = threadIdx.x;
  const long cb4 = ((long)t*2 + b)*4;
  const float* outv = ws + OFF_DELTA;

  if (tid < 96) dsumL[tid] = DsArr[tid] + DsArr[96+tid] + DsArr[192+tid] + DsArr[288+tid];
  __syncthreads();

  const float* finB = Fin + ((long)b*192 + t*96) * 4096;
  for (int i = tid; i < 96*64; i += 256) {
    int d = i >> 6, w = i & 63;
    int l  = (h << 6) | w;
    int lt = (w << 6) | h;
    float v0 = outv[((cb4+0)*96 + d)*4096 + l];
    float v1 = outv[((cb4+1)*96 + d)*4096 + lt];
    float v2 = outv[((cb4+2)*96 + d)*4096 + (4095 - l)];
    float v3 = outv[((cb4+3)*96 + d)*4096 + (4095 - lt)];
    sY[d][w] = v0 + v1 + v2 + v3 + finB[d*4096 + l] * dsumL[d];
  }
  __syncthreads();

  {
    int w = tid & 63, part = tid >> 6;
    float s = 0.f, q = 0.f;
    #pragma unroll
    for (int j = 0; j < 24; ++j) {
      float v = sY[part*24 + j][w];
      s += v; q += v*v;
    }
    pS[part][w] = s; pQ[part][w] = q;
  }
  __syncthreads();
  if (tid < 64) {
    int w = tid;
    float s = pS[0][w] + pS[1][w] + pS[2][w] + pS[3][w];
    float q = pQ[0][w] + pQ[1][w] + pQ[2][w] + pQ[3][w];
    float m = s * (1.0f/96.0f);
    float var = q * (1.0f/96.0f) - m*m;
    mv[w] = m;
    rs[w] = rsqrtf(var + 1e-5f);
  }
  __syncthreads();

  const long obase = (((long)t*2 + b)*4096 + (long)h*64)*96;
  for (int i = tid; i < 96*64; i += 256) {
    int w = i / 96, d = i - w*96;
    float v = (sY[d][w] - mv[w]) * rs[w] * gamma[d] + beta[d];
    outp[obase + (long)w*96 + d] = v;
  }
}

// ---------------------------------------------------------------------------
extern "C" void kernel_launch(void* const* d_in, const int* in_sizes, int n_in,
                              void* d_out, int out_size, void* d_ws, size_t ws_size,
                              hipStream_t stream)
{
  const float* Fin   = (const float*)d_in[0];
  const float* xproj = (const float*)d_in[1];
  const float* dtw   = (const float*)d_in[2];
  const float* dtb   = (const float*)d_in[3];
  const float* Alog  = (const float*)d_in[4];
  const float* Ds    = (const float*)d_in[5];
  const float* w1    = (const float*)d_in[6];
  const float* b1    = (const float*)d_in[7];
  const float* w2    = (const float*)d_in[8];
  const float* b2    = (const float*)d_in[9];
  const float* w3    = (const float*)d_in[10];
  const float* b3    = (const float*)d_in[11];
  const float* gamma = (const float*)d_in[12];
  const float* beta  = (const float*)d_in[13];
  float* ws   = (float*)d_ws;
  float* outp = (float*)d_out;

  ss2d_prep <<<dim3(1024), dim3(256), 0, stream>>>(Fin, xproj, dtw, dtb, ws);
  ss2d_scan <<<dim3(192),  dim3(64),  0, stream>>>(Alog, w1, b1, w2, b2, w3, b3, ws);
  ss2d_final<<<dim3(256),  dim3(256), 0, stream>>>(ws, Fin, Ds, gamma, beta, outp);
}

// Round 3
// 584.600 us; speedup vs baseline: 4.4164x; 1.1777x over previous
//
#include <hip/hip_runtime.h>
#include <math.h>

// Problem constants: B=2, d_model=192 -> 2 cores of c=96, K=4, d_state=8,
// dt_rank=12, H=W=64, L=4096.

// ws layout in floats:
//  delta [t3][d][l] : 16*96*4096 = 6291456   (t3 = (core*2+b)*4+k)
//  du    [t3][d][l] : 6291456                (du = delta * xs)
//  Bst   [t3][l/4][n][4] : 16*4096*8 = 524288
//  Cst   [t3][l/4][n][4] : 524288
//  outv  : ALIASES delta (row consumed >=16 steps ahead of the write)
#define OFF_DELTA 0L
#define OFF_DU    6291456L
#define OFF_BST   12582912L
#define OFF_CST   13107200L

#define QPX1 0xB1   // quad_perm [1,0,3,2]  -> lane ^ 1
#define QPX2 0x4E   // quad_perm [2,3,0,1]  -> lane ^ 2
#define QPX3 0x1B   // quad_perm [3,2,1,0]  -> lane ^ 3
#define RHM  0x141  // row_half_mirror      -> lane ^ 7 (within 8)

template<int CTRL>
__device__ __forceinline__ float dppf(float x) {
  int r = __builtin_amdgcn_update_dpp(0, __float_as_int(x), CTRL, 0xF, 0xF, true);
  return __int_as_float(r);
}

__device__ __forceinline__ float softplus_f(float x) {
  return fmaxf(x, 0.0f) + log1pf(expf(-fabsf(x)));
}

// compile-time component select from a float4 pair (s must be a constant
// after unrolling -> folds to a direct register reference, no scratch)
__device__ __forceinline__ float fc(const float4& a, const float4& b, int s) {
  switch (s & 7) {
    case 0: return a.x; case 1: return a.y; case 2: return a.z; case 3: return a.w;
    case 4: return b.x; case 5: return b.y; case 6: return b.z; default: return b.w;
  }
}

// ---------------------------------------------------------------------------
// Kernel 1: per (core,b,k, l-tile of 64): stage xs tile in LDS, compute
// x_dbl, write Bs,Cs (interleaved [l/4][n][4]) and delta + du = delta*xs.
// ---------------------------------------------------------------------------
__global__ __launch_bounds__(256) void ss2d_prep(
    const float* __restrict__ Fin,    // [2][192][4096]
    const float* __restrict__ xproj,  // [4][28][96]
    const float* __restrict__ dtw,    // [4][96][12]
    const float* __restrict__ dtb,    // [4][96]
    float* __restrict__ ws)
{
  __shared__ float xt[96][64];
  __shared__ float wp[28][96];
  __shared__ float dwL[96][12];
  __shared__ float dtbL[96];
  __shared__ float dtsL[12][64];

  const int bid  = blockIdx.x;
  const int tile = bid & 63;
  const int k    = (bid >> 6) & 3;
  const int b    = (bid >> 8) & 1;
  const int core = bid >> 9;
  const int tid  = threadIdx.x;
  const int l0   = tile << 6;
  const int h0   = tile;

  float* wpf = &wp[0][0];
  for (int i = tid; i < 28*96; i += 256) wpf[i] = xproj[k*28*96 + i];
  float* dwf = &dwL[0][0];
  for (int i = tid; i < 96*12; i += 256) dwf[i] = dtw[k*96*12 + i];
  if (tid < 96) dtbL[tid] = dtb[k*96 + tid];

  const float* finB = Fin + ((long)b*192 + core*96) * 4096;
  for (int i = tid; i < 96*64; i += 256) {
    int d = i >> 6, ll = i & 63;
    int l = l0 + ll;
    int pos;
    if (k == 0)      pos = l;
    else if (k == 1) pos = (ll << 6) | h0;
    else if (k == 2) pos = 4095 - l;
    else             pos = 4095 - ((ll << 6) | h0);
    xt[d][ll] = finB[d*4096 + pos];
  }
  __syncthreads();

  const int cbk = (core*2 + b)*4 + k;

  for (int i = tid; i < 28*64; i += 256) {
    int cc = i >> 6, ll = i & 63;
    float acc = 0.f;
    for (int d = 0; d < 96; ++d) acc += xt[d][ll] * wp[cc][d];
    int l = l0 + ll;
    if (cc < 12) {
      dtsL[cc][ll] = acc;
    } else {
      long base = (long)cbk*32768 + (long)(l >> 2)*32 + (l & 3);
      if (cc < 20) ws[OFF_BST + base + (cc-12)*4] = acc;
      else         ws[OFF_CST + base + (cc-20)*4] = acc;
    }
  }
  __syncthreads();

  for (int i = tid; i < 96*64; i += 256) {
    int d = i >> 6, ll = i & 63;
    float s = dtbL[d];
    #pragma unroll
    for (int r = 0; r < 12; ++r) s += dtsL[r][ll] * dwL[d][r];
    float dl = softplus_f(s);
    long off = ((long)cbk*96 + d)*4096 + l0 + ll;
    ws[OFF_DELTA + off] = dl;
    ws[OFF_DU    + off] = dl * xt[d][ll];
  }
}

// ---------------------------------------------------------------------------
// Kernel 2: sequential scan. 8 lanes per (t3,d) scan, lane = state index n.
// Cross-lane via DPP (VALU pipe). Balanced-tree MLP dot (chain ~5-6 dep ops
// per layer instead of 8+). All stream buffers in named float4 registers,
// double-buffered via a 2x-unrolled loop (no unions, no copies, no scratch).
// ---------------------------------------------------------------------------
__device__ __forceinline__ float mlp_layer(float h, const float wl[8], float bv) {
  float v1 = dppf<QPX1>(h);
  float v2 = dppf<QPX2>(h);
  float v3 = dppf<QPX3>(h);
  float v7 = dppf<RHM>(h);
  float v6 = dppf<RHM>(v1);
  float v5 = dppf<RHM>(v2);
  float v4 = dppf<RHM>(v3);
  // balanced tree; 0/1-hop values in the early chain, 2-hop values late
  float p0 = fmaf(v1, wl[1], fmaf(h,  wl[0], bv));
  float p1 = fmaf(v3, wl[3], v2 * wl[2]);
  float p2 = fmaf(v5, wl[5], v4 * wl[4]);
  float p3 = fmaf(v7, wl[7], v6 * wl[6]);
  return (p0 + p1) + (p2 + p3);
}

__global__ __launch_bounds__(64) void ss2d_scan(
    const float* __restrict__ Alogs,  // [4][96][8]
    const float* __restrict__ w1, const float* __restrict__ b1,
    const float* __restrict__ w2, const float* __restrict__ b2,
    const float* __restrict__ w3, const float* __restrict__ b3,
    float* __restrict__ ws)
{
  const int tid  = threadIdx.x;
  const int n    = tid & 7;
  const int G    = blockIdx.x * 8 + (tid >> 3);
  const int d    = G % 96;
  const int t3   = G / 96;
  const int k    = t3 & 3;

  float wl1[8], wl2[8], wl3[8];
  #pragma unroll
  for (int t = 0; t < 8; ++t) {
    int i = n ^ t;
    wl1[t] = w1[n*8 + i];
    wl2[t] = w2[n*8 + i];
    wl3[t] = w3[n*8 + i];
  }
  const float b1v = b1[n], b2v = b2[n], b3v = b3[n];
  const float a2  = -expf(Alogs[(k*96 + d)*8 + n]) * 1.4426950408889634f;

  const float4* dQ = (const float4*)(ws + OFF_DELTA + ((long)t3*96 + d)*4096);
  const float4* uQ = (const float4*)(ws + OFF_DU    + ((long)t3*96 + d)*4096);
  float*       outP = ws + OFF_DELTA + ((long)t3*96 + d)*4096;  // alias
  const float4* bQ = (const float4*)(ws + OFF_BST) + (long)t3*8192 + n;
  const float4* cQ = (const float4*)(ws + OFF_CST) + (long)t3*8192 + n;

  float4 dA0,dA1,uA0,uA1,bA0,bA1,cA0,cA1;   // buffer set A
  float4 dB0,dB1,uB0,uB1,bB0,bB1,cB0,cB1;   // buffer set B

#define LOADA(pb) do { long qb = (long)(pb); \
    dA0 = dQ[qb*2]; dA1 = dQ[qb*2+1]; \
    uA0 = uQ[qb*2]; uA1 = uQ[qb*2+1]; \
    bA0 = bQ[qb*16]; bA1 = bQ[qb*16+8]; \
    cA0 = cQ[qb*16]; cA1 = cQ[qb*16+8]; } while(0)
#define LOADB(pb) do { long qb = (long)(pb); \
    dB0 = dQ[qb*2]; dB1 = dQ[qb*2+1]; \
    uB0 = uQ[qb*2]; uB1 = uQ[qb*2+1]; \
    bB0 = bQ[qb*16]; bB1 = bQ[qb*16+8]; \
    cB0 = cQ[qb*16]; cB1 = cQ[qb*16+8]; } while(0)

  LOADA(0);
  LOADB(1);

  float h = 0.f;

  auto process = [&](const float4& d0, const float4& d1,
                     const float4& u0, const float4& u1,
                     const float4& B0, const float4& B1,
                     const float4& C0, const float4& C1, int l0) {
    float o[8];
    #pragma unroll
    for (int s = 0; s < 8; ++s) {
      float t1 = fmaxf(mlp_layer(h,  wl1, b1v), 0.f);
      float t2 = fmaxf(mlp_layer(t1, wl2, b2v), 0.f);
      float hw = mlp_layer(t2, wl3, b3v);
      float dA  = __builtin_amdgcn_exp2f(fc(d0,d1,s) * a2);
      float dBu = fc(u0,u1,s) * fc(B0,B1,s);
      h = fmaf(dA, h, hw * dBu);
      float p = h * fc(C0,C1,s);
      p += dppf<QPX1>(p);
      p += dppf<QPX2>(p);
      p += dppf<RHM>(p);
      o[s] = p;
    }
    if (n == 0) {
      *(float4*)(outP + l0)     = make_float4(o[0],o[1],o[2],o[3]);
      *(float4*)(outP + l0 + 4) = make_float4(o[4],o[5],o[6],o[7]);
    }
  };

  for (int it = 0; it < 256; ++it) {
    const int blk = it*2;
    process(dA0,dA1,uA0,uA1,bA0,bA1,cA0,cA1, blk*8);
    { const int pb = (blk+2 < 512) ? blk+2 : 511; LOADA(pb); }
    process(dB0,dB1,uB0,uB1,bB0,bB1,cB0,cB1, (blk+1)*8);
    { const int pb = (blk+3 < 512) ? blk+3 : 511; LOADB(pb); }
  }
#undef LOADA
#undef LOADB
}

// ---------------------------------------------------------------------------
// Kernel 3: per (core,b,h): gather 4 directional terms (index transforms),
// add Fin*sum_k(Ds) (the xs*Ds skip term collapses to this after the
// inverse transforms), sum, layernorm over c=96, write coalesced.
// ---------------------------------------------------------------------------
__global__ __launch_bounds__(256) void ss2d_final(
    const float* __restrict__ ws,
    const float* __restrict__ Fin,
    const float* __restrict__ DsArr,   // [4][96]
    const float* __restrict__ gamma,
    const float* __restrict__ beta,
    float* __restrict__ outp)
{
  __shared__ float sY[96][65];
  __shared__ float pS[4][64];
  __shared__ float pQ[4][64];
  __shared__ float mv[64];
  __shared__ float rs[64];
  __shared__ float dsumL[96];

  const int bid = blockIdx.x;
  const int h   = bid & 63;
  const int b   = (bid >> 6) & 1;
  const int t   = (bid >> 7) & 1;   // core
  const int tid = threadIdx.x;
  const long cb4 = ((long)t*2 + b)*4;
  const float* outv = ws + OFF_DELTA;

  if (tid < 96) dsumL[tid] = DsArr[tid] + DsArr[96+tid] + DsArr[192+tid] + DsArr[288+tid];
  __syncthreads();

  const float* finB = Fin + ((long)b*192 + t*96) * 4096;
  for (int i = tid; i < 96*64; i += 256) {
    int d = i >> 6, w = i & 63;
    int l  = (h << 6) | w;
    int lt = (w << 6) | h;
    float v0 = outv[((cb4+0)*96 + d)*4096 + l];
    float v1 = outv[((cb4+1)*96 + d)*4096 + lt];
    float v2 = outv[((cb4+2)*96 + d)*4096 + (4095 - l)];
    float v3 = outv[((cb4+3)*96 + d)*4096 + (4095 - lt)];
    sY[d][w] = v0 + v1 + v2 + v3 + finB[d*4096 + l] * dsumL[d];
  }
  __syncthreads();

  {
    int w = tid & 63, part = tid >> 6;
    float s = 0.f, q = 0.f;
    #pragma unroll
    for (int j = 0; j < 24; ++j) {
      float v = sY[part*24 + j][w];
      s += v; q += v*v;
    }
    pS[part][w] = s; pQ[part][w] = q;
  }
  __syncthreads();
  if (tid < 64) {
    int w = tid;
    float s = pS[0][w] + pS[1][w] + pS[2][w] + pS[3][w];
    float q = pQ[0][w] + pQ[1][w] + pQ[2][w] + pQ[3][w];
    float m = s * (1.0f/96.0f);
    float var = q * (1.0f/96.0f) - m*m;
    mv[w] = m;
    rs[w] = rsqrtf(var + 1e-5f);
  }
  __syncthreads();

  const long obase = (((long)t*2 + b)*4096 + (long)h*64)*96;
  for (int i = tid; i < 96*64; i += 256) {
    int w = i / 96, d = i - w*96;
    float v = (sY[d][w] - mv[w]) * rs[w] * gamma[d] + beta[d];
    outp[obase + (long)w*96 + d] = v;
  }
}

// ---------------------------------------------------------------------------
extern "C" void kernel_launch(void* const* d_in, const int* in_sizes, int n_in,
                              void* d_out, int out_size, void* d_ws, size_t ws_size,
                              hipStream_t stream)
{
  const float* Fin   = (const float*)d_in[0];
  const float* xproj = (const float*)d_in[1];
  const float* dtw   = (const float*)d_in[2];
  const float* dtb   = (const float*)d_in[3];
  const float* Alog  = (const float*)d_in[4];
  const float* Ds    = (const float*)d_in[5];
  const float* w1    = (const float*)d_in[6];
  const float* b1    = (const float*)d_in[7];
  const float* w2    = (const float*)d_in[8];
  const float* b2    = (const float*)d_in[9];
  const float* w3    = (const float*)d_in[10];
  const float* b3    = (const float*)d_in[11];
  const float* gamma = (const float*)d_in[12];
  const float* beta  = (const float*)d_in[13];
  float* ws   = (float*)d_ws;
  float* outp = (float*)d_out;

  ss2d_prep <<<dim3(1024), dim3(256), 0, stream>>>(Fin, xproj, dtw, dtb, ws);
  ss2d_scan <<<dim3(192),  dim3(64),  0, stream>>>(Alog, w1, b1, w2, b2, w3, b3, ws);
  ss2d_final<<<dim3(256),  dim3(256), 0, stream>>>(ws, Fin, Ds, gamma, beta, outp);
}